// Round 3
// baseline (562.334 us; speedup 1.0000x reference)
//
#include <hip/hip_runtime.h>
#include <hip/hip_bf16.h>
#include <math.h>

typedef unsigned short u16;
typedef __attribute__((ext_vector_type(8))) short short8;
typedef __attribute__((ext_vector_type(4))) float f32x4;
typedef __attribute__((ext_vector_type(4))) unsigned short u16x4;

// Problem constants
#define NWIN 32768      // B*T*nh*nw = 128*256 windows
#define ROWSTRIDE (32*384)

__device__ __forceinline__ float b2f(u16 v) {
  unsigned int u = ((unsigned int)v) << 16;
  return __builtin_bit_cast(float, u);
}
__device__ __forceinline__ u16 f2b(float f) {
  unsigned int u = __builtin_bit_cast(unsigned int, f);
  unsigned int r = (u + 0x7fffu + ((u >> 16) & 1u)) >> 16;
  return (u16)r;
}

// ---------------- prologue folds (tiny) ----------------
// WqkT[n][k] = sum_d Wk[n][d] * Wq[k][d]   (= (Wq @ Wk^T) transposed), bf16
__global__ void fold_qk(const float* __restrict__ Wq, const float* __restrict__ Wk,
                        u16* __restrict__ WqkT) {
  __shared__ float a[16][17];
  __shared__ float b[16][17];
  const int tx = threadIdx.x, ty = threadIdx.y;
  const int k0 = blockIdx.x * 16, n0 = blockIdx.y * 16;
  float acc = 0.f;
  for (int d0 = 0; d0 < 384; d0 += 16) {
    a[ty][tx] = Wk[(n0 + ty) * 384 + d0 + tx];
    b[ty][tx] = Wq[(k0 + ty) * 384 + d0 + tx];
    __syncthreads();
#pragma unroll
    for (int dd = 0; dd < 16; ++dd) acc += a[ty][dd] * b[tx][dd];
    __syncthreads();
  }
  WqkT[(n0 + ty) * 384 + k0 + tx] = f2b(acc);
}

// bqk[n] = sum_d bq[d] * Wk[n][d]
__global__ void bias_qk(const float* __restrict__ bq, const float* __restrict__ Wk,
                        float* __restrict__ bqk) {
  const int n = blockIdx.x * 128 + threadIdx.x;
  float s = 0.f;
  for (int d = 0; d < 384; ++d) s += bq[d] * Wk[n * 384 + d];
  bqk[n] = s;
}

// W1pT[n][k] = sum_d Wv[k][d] * W1[d][n]   (= (Wv @ W1) transposed), n<768,k<384
__global__ void fold_v1(const float* __restrict__ Wv, const float* __restrict__ W1,
                        u16* __restrict__ W1pT) {
  __shared__ float a[16][17];  // a[dl][nl] = W1[d0+dl][n0+nl]
  __shared__ float b[16][17];  // b[kl][dl] = Wv[k0+kl][d0+dl]
  const int tx = threadIdx.x, ty = threadIdx.y;
  const int n0 = blockIdx.x * 16, k0 = blockIdx.y * 16;
  float acc = 0.f;
  for (int d0 = 0; d0 < 384; d0 += 16) {
    a[ty][tx] = W1[(d0 + ty) * 768 + n0 + tx];
    b[ty][tx] = Wv[(k0 + ty) * 384 + d0 + tx];
    __syncthreads();
#pragma unroll
    for (int dd = 0; dd < 16; ++dd) acc += b[tx][dd] * a[dd][ty];
    __syncthreads();
  }
  W1pT[(n0 + ty) * 384 + k0 + tx] = f2b(acc);
}

// b1p[n] = b1[n] + sum_d bv[d] * W1[d][n]
__global__ void bias_v1(const float* __restrict__ bv, const float* __restrict__ W1,
                        const float* __restrict__ b1, float* __restrict__ b1p) {
  const int n = blockIdx.x * 256 + threadIdx.x;
  float s = b1[n];
  for (int d = 0; d < 384; ++d) s += bv[d] * W1[d * 768 + n];
  b1p[n] = s;
}

// W2T[n][k] = W2[k][n], n<384, k<768, bf16
__global__ void tw2(const float* __restrict__ W2, u16* __restrict__ W2T) {
  const int g = blockIdx.x * 256 + threadIdx.x;  // < 294912
  const int n = g / 768, k = g - n * 768;
  W2T[g] = f2b(W2[k * 384 + n]);
}

// ---------------- pass 1: window mean (fp32 -> bf16) ----------------
__global__ void mean_kernel(const float* __restrict__ x, u16* __restrict__ xm) {
  const int g = blockIdx.x * 256 + threadIdx.x;  // < 32768*96
  const int w = g / 96;
  const int dv = g - w * 96;
  const int bt = w >> 8;
  const int ij = w & 255;
  const int i = ij >> 4, j = ij & 15;
  const float* xb = x + (size_t)((bt * 32 + 2 * i) * 32 + 2 * j) * 384 + dv * 4;
  const float4 a = *(const float4*)(xb);
  const float4 b = *(const float4*)(xb + 384);
  const float4 c = *(const float4*)(xb + ROWSTRIDE);
  const float4 d = *(const float4*)(xb + ROWSTRIDE + 384);
  u16x4 o;
  o.x = f2b(0.25f * (a.x + b.x + c.x + d.x));
  o.y = f2b(0.25f * (a.y + b.y + c.y + d.y));
  o.z = f2b(0.25f * (a.z + b.z + c.z + d.z));
  o.w = f2b(0.25f * (a.w + b.w + c.w + d.w));
  *(u16x4*)(xm + (size_t)w * 384 + dv * 4) = o;
}

// ---------------- MFMA GEMM: C[M][N] = A[M][K] @ B, B given as BT[N][K] ----------------
// BM=BN=128, BK=64, 4 waves (2x2), wave tile 64x64, 16x16x32 bf16 MFMA.
// EPI: 0 = +bias, bf16 store; 1 = +bias, exact GELU, bf16 store.
template <int EPI>
__global__ __launch_bounds__(256) void gemm_bt(const u16* __restrict__ A,
                                               const u16* __restrict__ BT,
                                               const float* __restrict__ bias,
                                               u16* __restrict__ C, int N, int K) {
  __shared__ __align__(16) u16 As[128 * 64];
  __shared__ __align__(16) u16 Bs[128 * 64];
  const int tid = threadIdx.x;
  const int lane = tid & 63;
  const int wid = tid >> 6;
  const int wr = wid >> 1, wc = wid & 1;
  const int bm = blockIdx.x * 128;
  const int bn = blockIdx.y * 128;
  const int l15 = lane & 15;
  const int l4 = lane >> 4;

  f32x4 acc[4][4] = {};

  for (int kt = 0; kt < K; kt += 64) {
#pragma unroll
    for (int i = 0; i < 4; ++i) {
      const int c = i * 256 + tid;
      const int row = c >> 3, c8 = c & 7;
      const u16* ga = A + (size_t)(bm + row) * K + kt + c8 * 8;
      __builtin_amdgcn_global_load_lds((const __attribute__((address_space(1))) void*)ga,
                                       (__attribute__((address_space(3))) void*)&As[c * 8],
                                       16, 0, 0);
    }
#pragma unroll
    for (int i = 0; i < 4; ++i) {
      const int c = i * 256 + tid;
      const int row = c >> 3, c8 = c & 7;
      const u16* gb = BT + (size_t)(bn + row) * K + kt + c8 * 8;
      __builtin_amdgcn_global_load_lds((const __attribute__((address_space(1))) void*)gb,
                                       (__attribute__((address_space(3))) void*)&Bs[c * 8],
                                       16, 0, 0);
    }
    __syncthreads();
#pragma unroll
    for (int kk = 0; kk < 2; ++kk) {
      short8 af[4], bf[4];
#pragma unroll
      for (int mi = 0; mi < 4; ++mi)
        af[mi] = *(const short8*)&As[(wr * 64 + mi * 16 + l15) * 64 + kk * 32 + l4 * 8];
#pragma unroll
      for (int ni = 0; ni < 4; ++ni)
        bf[ni] = *(const short8*)&Bs[(wc * 64 + ni * 16 + l15) * 64 + kk * 32 + l4 * 8];
#pragma unroll
      for (int mi = 0; mi < 4; ++mi)
#pragma unroll
        for (int ni = 0; ni < 4; ++ni)
          acc[mi][ni] = __builtin_amdgcn_mfma_f32_16x16x32_bf16(af[mi], bf[ni], acc[mi][ni], 0, 0, 0);
    }
    __syncthreads();
  }

#pragma unroll
  for (int mi = 0; mi < 4; ++mi) {
#pragma unroll
    for (int ni = 0; ni < 4; ++ni) {
      const int col = bn + wc * 64 + ni * 16 + l15;
      const float bs = bias[col];
#pragma unroll
      for (int r = 0; r < 4; ++r) {
        const int row = bm + wr * 64 + mi * 16 + l4 * 4 + r;
        float v = acc[mi][ni][r] + bs;
        if (EPI == 1) v = 0.5f * v * (1.0f + erff(v * 0.70710678118654752f));
        C[(size_t)row * N + col] = f2b(v);
      }
    }
  }
}

// ---------------- pass 3: attention combine ----------------
// logits_i = (x_i . u_w) * scale; a = softmax; A[w] = sum_i a_i * x_i  (bf16)
__global__ void attn_kernel(const float* __restrict__ x, const u16* __restrict__ U,
                            u16* __restrict__ Aout) {
  const int tid = threadIdx.x;
  const int lane = tid & 63;
  const int w = blockIdx.x * 4 + (tid >> 6);
  const int bt = w >> 8;
  const int ij = w & 255;
  const int i = ij >> 4, j = ij & 15;
  const float* xb = x + (size_t)((bt * 32 + 2 * i) * 32 + 2 * j) * 384;
  float xv0[6], xv1[6], xv2[6], xv3[6];
  float d0 = 0.f, d1 = 0.f, d2 = 0.f, d3 = 0.f;
#pragma unroll
  for (int r = 0; r < 6; ++r) {
    const int d = r * 64 + lane;
    const float u = b2f(U[(size_t)w * 384 + d]);
    const float a = xb[d];
    const float b = xb[384 + d];
    const float c = xb[ROWSTRIDE + d];
    const float e = xb[ROWSTRIDE + 384 + d];
    xv0[r] = a; xv1[r] = b; xv2[r] = c; xv3[r] = e;
    d0 += a * u; d1 += b * u; d2 += c * u; d3 += e * u;
  }
#pragma unroll
  for (int off = 32; off > 0; off >>= 1) {
    d0 += __shfl_xor(d0, off, 64);
    d1 += __shfl_xor(d1, off, 64);
    d2 += __shfl_xor(d2, off, 64);
    d3 += __shfl_xor(d3, off, 64);
  }
  const float scale = 0.05103103630798287f;  // 384^-0.5
  const float l0 = d0 * scale, l1 = d1 * scale, l2 = d2 * scale, l3 = d3 * scale;
  const float m = fmaxf(fmaxf(l0, l1), fmaxf(l2, l3));
  const float e0 = __expf(l0 - m), e1 = __expf(l1 - m), e2 = __expf(l2 - m), e3 = __expf(l3 - m);
  const float inv = 1.0f / (e0 + e1 + e2 + e3);
#pragma unroll
  for (int r = 0; r < 6; ++r) {
    const float a = (e0 * xv0[r] + e1 * xv1[r] + e2 * xv2[r] + e3 * xv3[r]) * inv;
    Aout[(size_t)w * 384 + r * 64 + lane] = f2b(a);
  }
}

// ---------------- pass 6: LayerNorm (bf16 in, fp32 out) ----------------
__global__ void ln_kernel(const u16* __restrict__ Y, const float* __restrict__ gamma,
                          const float* __restrict__ beta, float* __restrict__ out) {
  const int tid = threadIdx.x;
  const int lane = tid & 63;
  const int w = blockIdx.x * 4 + (tid >> 6);
  float v[6];
  float s1 = 0.f, s2 = 0.f;
#pragma unroll
  for (int r = 0; r < 6; ++r) {
    v[r] = b2f(Y[(size_t)w * 384 + r * 64 + lane]);
    s1 += v[r];
    s2 += v[r] * v[r];
  }
#pragma unroll
  for (int off = 32; off > 0; off >>= 1) {
    s1 += __shfl_xor(s1, off, 64);
    s2 += __shfl_xor(s2, off, 64);
  }
  const float mu = s1 * (1.0f / 384.0f);
  const float var = s2 * (1.0f / 384.0f) - mu * mu;
  const float rstd = rsqrtf(var + 1e-5f);
#pragma unroll
  for (int r = 0; r < 6; ++r) {
    const int d = r * 64 + lane;
    out[(size_t)w * 384 + d] = (v[r] - mu) * rstd * gamma[d] + beta[d];
  }
}

// ---------------- launch ----------------
extern "C" void kernel_launch(void* const* d_in, const int* in_sizes, int n_in,
                              void* d_out, int out_size, void* d_ws, size_t ws_size,
                              hipStream_t stream) {
  const float* x     = (const float*)d_in[0];
  const float* Wq    = (const float*)d_in[1];
  const float* bq    = (const float*)d_in[2];
  const float* Wk    = (const float*)d_in[3];
  // d_in[4] = bk: cancels in softmax, unused
  const float* Wv    = (const float*)d_in[5];
  const float* bv    = (const float*)d_in[6];
  const float* W1    = (const float*)d_in[7];
  const float* b1    = (const float*)d_in[8];
  const float* W2    = (const float*)d_in[9];
  const float* b2    = (const float*)d_in[10];
  const float* gamma = (const float*)d_in[11];
  const float* beta  = (const float*)d_in[12];

  char* ws = (char*)d_ws;
  // lifetimes: Xmean [K1..K2], U [K2..K3], A [K3..K4], H [K4..K5], Ypre [K5..K6]
  u16* Xmean = (u16*)(ws + 0);           // 25165824 B ; reused as A after K2
  u16* Abuf  = Xmean;
  u16* Ubuf  = (u16*)(ws + 25165824);    // 25165824 B ; reused as Ypre after K3
  u16* Ypre  = Ubuf;
  u16* Hbuf  = (u16*)(ws + 50331648);    // 50331648 B
  char* wb   = ws + 100663296;
  u16*  WqkT = (u16*)(wb);               // 294912 B
  u16*  W1pT = (u16*)(wb + 294912);      // 589824 B
  u16*  W2T  = (u16*)(wb + 884736);      // 589824 B
  float* bqk = (float*)(wb + 1474560);   // 1536 B
  float* b1p = (float*)(wb + 1476096);   // 3072 B

  // prologue folds
  fold_qk<<<dim3(24, 24), dim3(16, 16), 0, stream>>>(Wq, Wk, WqkT);
  bias_qk<<<3, 128, 0, stream>>>(bq, Wk, bqk);
  fold_v1<<<dim3(48, 24), dim3(16, 16), 0, stream>>>(Wv, W1, W1pT);
  bias_v1<<<3, 256, 0, stream>>>(bv, W1, b1, b1p);
  tw2<<<1152, 256, 0, stream>>>(W2, W2T);

  // K1: window means
  mean_kernel<<<12288, 256, 0, stream>>>(x, Xmean);
  // K2: U = Xmean @ Wqk + bqk   (M=32768, N=384, K=384)
  gemm_bt<0><<<dim3(256, 3), 256, 0, stream>>>(Xmean, WqkT, bqk, Ubuf, 384, 384);
  // K3: softmax-combine -> A
  attn_kernel<<<8192, 256, 0, stream>>>(x, Ubuf, Abuf);
  // K4: H = gelu(A @ W1p + b1p)  (N=768, K=384)
  gemm_bt<1><<<dim3(256, 6), 256, 0, stream>>>(Abuf, W1pT, b1p, Hbuf, 768, 384);
  // K5: Ypre = H @ W2 + b2       (N=384, K=768)
  gemm_bt<0><<<dim3(256, 3), 256, 0, stream>>>(Hbuf, W2T, b2, Ypre, 384, 768);
  // K6: LayerNorm -> out (fp32)
  ln_kernel<<<8192, 256, 0, stream>>>(Ypre, gamma, beta, (float*)d_out);
}

// Round 4
// 479.941 us; speedup vs baseline: 1.1717x; 1.1717x over previous
//
#include <hip/hip_runtime.h>
#include <hip/hip_bf16.h>
#include <math.h>

typedef unsigned short u16;
typedef __attribute__((ext_vector_type(8))) short short8;
typedef __attribute__((ext_vector_type(4))) float f32x4;
typedef __attribute__((ext_vector_type(4))) unsigned short u16x4;

#define NWIN 32768
#define ROWSTRIDE (32*384)

__device__ __forceinline__ float b2f(u16 v) {
  unsigned int u = ((unsigned int)v) << 16;
  return __builtin_bit_cast(float, u);
}
__device__ __forceinline__ u16 f2b(float f) {
  unsigned int u = __builtin_bit_cast(unsigned int, f);
  unsigned int r = (u + 0x7fffu + ((u >> 16) & 1u)) >> 16;
  return (u16)r;
}

// ================= prologue: all weight folds in one kernel =================
// blocks [0,576): WqkT[n][k] = sum_d Wk[n][d]*Wq[k][d]           (384x384 bf16)
// blocks [576,1728): W1pT[n][k] = sum_d Wv[k][d]*W1[d][n]        (768x384 bf16)
// blocks [1728,2880): W2T[n][k] = W2[k][n]                       (384x768 bf16)
// blocks [2880,2976): bqk[n] = sum_d bq[d]*Wk[n][d]              (384 f32)
// blocks [2976,3168): b1p[n] = b1[n] + sum_d bv[d]*W1[d][n]      (768 f32)
__global__ __launch_bounds__(256) void prologue(
    const float* __restrict__ Wq, const float* __restrict__ bq,
    const float* __restrict__ Wk, const float* __restrict__ Wv,
    const float* __restrict__ bv, const float* __restrict__ W1,
    const float* __restrict__ b1, const float* __restrict__ W2,
    u16* __restrict__ WqkT, u16* __restrict__ W1pT, u16* __restrict__ W2T,
    float* __restrict__ bqk, float* __restrict__ b1p) {
  __shared__ float sa[16][17];
  __shared__ float sb[16][17];
  const int b = blockIdx.x, t = threadIdx.x;
  const int tx = t & 15, ty = t >> 4;
  if (b < 576) {
    const int k0 = (b % 24) * 16, n0 = (b / 24) * 16;
    float acc = 0.f;
    for (int d0 = 0; d0 < 384; d0 += 16) {
      sa[ty][tx] = Wk[(n0 + ty) * 384 + d0 + tx];
      sb[ty][tx] = Wq[(k0 + ty) * 384 + d0 + tx];
      __syncthreads();
#pragma unroll
      for (int dd = 0; dd < 16; ++dd) acc += sa[ty][dd] * sb[tx][dd];
      __syncthreads();
    }
    WqkT[(n0 + ty) * 384 + k0 + tx] = f2b(acc);
  } else if (b < 1728) {
    const int bb = b - 576;
    const int n0 = (bb % 48) * 16, k0 = (bb / 48) * 16;
    float acc = 0.f;
    for (int d0 = 0; d0 < 384; d0 += 16) {
      sa[ty][tx] = W1[(d0 + ty) * 768 + n0 + tx];
      sb[ty][tx] = Wv[(k0 + ty) * 384 + d0 + tx];
      __syncthreads();
#pragma unroll
      for (int dd = 0; dd < 16; ++dd) acc += sb[tx][dd] * sa[dd][ty];
      __syncthreads();
    }
    W1pT[(n0 + ty) * 384 + k0 + tx] = f2b(acc);
  } else if (b < 2880) {
    const int g = (b - 1728) * 256 + t;  // < 294912
    const int n = g / 768, k = g - n * 768;
    W2T[g] = f2b(W2[k * 384 + n]);
  } else if (b < 2976) {
    const int lane = t & 63;
    const int n = (b - 2880) * 4 + (t >> 6);
    float s = 0.f;
#pragma unroll
    for (int rr = 0; rr < 6; ++rr) {
      const int d = rr * 64 + lane;
      s += bq[d] * Wk[n * 384 + d];
    }
#pragma unroll
    for (int off = 32; off > 0; off >>= 1) s += __shfl_xor(s, off, 64);
    if (lane == 0) bqk[n] = s;
  } else {
    const int lane = t & 63;
    const int n = (b - 2976) * 4 + (t >> 6);
    float s = 0.f;
#pragma unroll
    for (int rr = 0; rr < 6; ++rr) {
      const int d = rr * 64 + lane;
      s += bv[d] * W1[(size_t)d * 768 + n];
    }
#pragma unroll
    for (int off = 32; off > 0; off >>= 1) s += __shfl_xor(s, off, 64);
    if (lane == 0) b1p[n] = s + b1[n];
  }
}

// ================= k2a: fused mean + U-GEMM + softmax-combine =================
// grid 256 blocks x 512 threads. Block = 128 windows x 384 cols.
// 8 waves, wave grid 2M x 4N, wave-tile 64x96 (4x6 frags of 16x16x32).
// A (window means, bf16) computed in-regs from x during staging (padded LDS).
// Epilogue: U -> LDS (two 64-row halves), attention combine, write Abuf.
#define AS_STRIDE 72   // 144B rows: 16B-aligned, rows shift 4 banks
__global__ __launch_bounds__(512) void k2a(const float* __restrict__ x,
                                           const u16* __restrict__ WqkT,
                                           const float* __restrict__ bqk,
                                           u16* __restrict__ Abuf) {
  __shared__ __align__(16) u16 smem[128 * AS_STRIDE + 384 * 64];  // 67.5 KB
  u16* As = smem;                       // [128][AS_STRIDE]
  u16* Bs = smem + 128 * AS_STRIDE;     // [384][64]
  u16* Ubuf = smem;                     // [64][388] alias (used after k-loop)

  const int tid = threadIdx.x;
  const int lane = tid & 63;
  const int wid = tid >> 6;
  const int wr = wid >> 2, wc = wid & 3;
  const int l15 = lane & 15;
  const int l4 = lane >> 4;
  const int bm = blockIdx.x * 128;

  f32x4 acc[4][6] = {};

  for (int k0 = 0; k0 < 384; k0 += 64) {
    // ---- stage A: compute window means from x (reg-staged, padded LDS) ----
#pragma unroll
    for (int s = 0; s < 4; ++s) {
      const int c = s * 512 + tid;           // < 2048
      const int row = c >> 4, d4 = c & 15;
      const int w = bm + row;
      const int bt = w >> 8, ij = w & 255;
      const int wi = ij >> 4, wj = ij & 15;
      const float* xb = x + (size_t)((bt * 32 + 2 * wi) * 32 + 2 * wj) * 384 + k0 + d4 * 4;
      const float4 p0 = *(const float4*)(xb);
      const float4 p1 = *(const float4*)(xb + 384);
      const float4 p2 = *(const float4*)(xb + ROWSTRIDE);
      const float4 p3 = *(const float4*)(xb + ROWSTRIDE + 384);
      u16x4 o;
      o.x = f2b(0.25f * (p0.x + p1.x + p2.x + p3.x));
      o.y = f2b(0.25f * (p0.y + p1.y + p2.y + p3.y));
      o.z = f2b(0.25f * (p0.z + p1.z + p2.z + p3.z));
      o.w = f2b(0.25f * (p0.w + p1.w + p2.w + p3.w));
      *(u16x4*)&As[row * AS_STRIDE + d4 * 4] = o;
    }
    // ---- stage B: WqkT chunk via global_load_lds ----
#pragma unroll
    for (int s = 0; s < 6; ++s) {
      const int c = s * 512 + tid;           // < 3072
      const int row = c >> 3, c8 = c & 7;
      const u16* gb = WqkT + (size_t)row * 384 + k0 + c8 * 8;
      __builtin_amdgcn_global_load_lds((const __attribute__((address_space(1))) void*)gb,
                                       (__attribute__((address_space(3))) void*)&Bs[c * 8],
                                       16, 0, 0);
    }
    __syncthreads();
#pragma unroll
    for (int kk = 0; kk < 2; ++kk) {
      short8 af[4], bf[6];
#pragma unroll
      for (int mi = 0; mi < 4; ++mi)
        af[mi] = *(const short8*)&As[(wr * 64 + mi * 16 + l15) * AS_STRIDE + kk * 32 + l4 * 8];
#pragma unroll
      for (int ni = 0; ni < 6; ++ni)
        bf[ni] = *(const short8*)&Bs[(wc * 96 + ni * 16 + l15) * 64 + kk * 32 + l4 * 8];
#pragma unroll
      for (int mi = 0; mi < 4; ++mi)
#pragma unroll
        for (int ni = 0; ni < 6; ++ni)
          acc[mi][ni] = __builtin_amdgcn_mfma_f32_16x16x32_bf16(af[mi], bf[ni], acc[mi][ni], 0, 0, 0);
    }
    __syncthreads();
  }

  // ---- epilogue: two 64-row halves: U->LDS, then attention combine ----
  const float scale = 0.05103103630798287f;  // 384^-0.5
#pragma unroll
  for (int h = 0; h < 2; ++h) {
    if (wr == h) {
#pragma unroll
      for (int mi = 0; mi < 4; ++mi)
#pragma unroll
        for (int ni = 0; ni < 6; ++ni) {
          const int col = wc * 96 + ni * 16 + l15;
          const float bk_ = bqk[col];
#pragma unroll
          for (int r = 0; r < 4; ++r) {
            const int lr = mi * 16 + l4 * 4 + r;
            Ubuf[lr * 388 + col] = f2b(acc[mi][ni][r] + bk_);
          }
        }
    }
    __syncthreads();
    // each wave handles 8 windows of this half
#pragma unroll
    for (int q = 0; q < 8; ++q) {
      const int lr = wid * 8 + q;
      const int w = bm + h * 64 + lr;
      const int bt = w >> 8, ij = w & 255;
      const int wi = ij >> 4, wj = ij & 15;
      const float* xb = x + (size_t)((bt * 32 + 2 * wi) * 32 + 2 * wj) * 384;
      float xv0[6], xv1[6], xv2[6], xv3[6];
      float d0 = 0.f, d1 = 0.f, d2 = 0.f, d3 = 0.f;
#pragma unroll
      for (int rr = 0; rr < 6; ++rr) {
        const int d = rr * 64 + lane;
        const float u = b2f(Ubuf[lr * 388 + d]);
        const float a = xb[d];
        const float b = xb[384 + d];
        const float c = xb[ROWSTRIDE + d];
        const float e = xb[ROWSTRIDE + 384 + d];
        xv0[rr] = a; xv1[rr] = b; xv2[rr] = c; xv3[rr] = e;
        d0 += a * u; d1 += b * u; d2 += c * u; d3 += e * u;
      }
#pragma unroll
      for (int off = 32; off > 0; off >>= 1) {
        d0 += __shfl_xor(d0, off, 64);
        d1 += __shfl_xor(d1, off, 64);
        d2 += __shfl_xor(d2, off, 64);
        d3 += __shfl_xor(d3, off, 64);
      }
      const float l0 = d0 * scale, l1 = d1 * scale, l2 = d2 * scale, l3 = d3 * scale;
      const float m = fmaxf(fmaxf(l0, l1), fmaxf(l2, l3));
      const float e0 = __expf(l0 - m), e1 = __expf(l1 - m), e2 = __expf(l2 - m), e3 = __expf(l3 - m);
      const float inv = 1.0f / (e0 + e1 + e2 + e3);
#pragma unroll
      for (int rr = 0; rr < 6; ++rr) {
        const float a = (e0 * xv0[rr] + e1 * xv1[rr] + e2 * xv2[rr] + e3 * xv3[rr]) * inv;
        Abuf[(size_t)w * 384 + rr * 64 + lane] = f2b(a);
      }
    }
    __syncthreads();
  }
}

// ================= mlp: fused GEMM1 + GELU + GEMM2 + LayerNorm =================
// grid 512 blocks x 512 threads. Block = 64 windows.
// GEMM1: 64x768 (K=384), 8 waves 1x8, wave-tile 64x96. H -> LDS (bf16, padded).
// GEMM2: 64x384 (K=768), 8 waves 1x8, wave-tile 64x48, A-frags read from H-LDS.
// LN fused in registers; fp32 out.
#define H_STRIDE 776   // 1552B rows: 16B-aligned, rows shift 4 banks
__global__ __launch_bounds__(512) void mlp(const u16* __restrict__ Abuf,
                                           const u16* __restrict__ W1pT,
                                           const float* __restrict__ b1p,
                                           const u16* __restrict__ W2T,
                                           const float* __restrict__ b2,
                                           const float* __restrict__ gamma,
                                           const float* __restrict__ beta,
                                           float* __restrict__ out) {
  __shared__ __align__(16) u16 smem[77824];  // 152 KB
  u16* B1 = smem;            // [768][64] during GEMM1 (96 KB)
  u16* A1 = smem + 49152;    // [64][64]  during GEMM1 (8 KB)
  u16* B2 = smem + 53248;    // [384][64] during GEMM2 (48 KB)
  u16* H  = smem;            // [64][H_STRIDE] after GEMM1 (97 KB, aliases B1+A1)
  float* P1 = (float*)&smem[53248];  // [64][8] LN partials (alias B2 after GEMM2)
  float* P2 = P1 + 512;
  float* MU = P1 + 1024;
  float* RS = P1 + 1088;

  const int tid = threadIdx.x;
  const int lane = tid & 63;
  const int wc = tid >> 6;   // 1x8 wave grid
  const int l15 = lane & 15;
  const int l4 = lane >> 4;
  const int w0 = blockIdx.x * 64;

  // ---------------- GEMM1: H = gelu(A @ W1p + b1p) ----------------
  f32x4 acc1[4][6] = {};
  for (int k0 = 0; k0 < 384; k0 += 64) {
    {
      const int row = tid >> 3, c8 = tid & 7;
      const u16* ga = Abuf + (size_t)(w0 + row) * 384 + k0 + c8 * 8;
      __builtin_amdgcn_global_load_lds((const __attribute__((address_space(1))) void*)ga,
                                       (__attribute__((address_space(3))) void*)&A1[tid * 8],
                                       16, 0, 0);
    }
#pragma unroll
    for (int s = 0; s < 12; ++s) {
      const int c = s * 512 + tid;           // < 6144
      const int row = c >> 3, c8 = c & 7;
      const u16* gb = W1pT + (size_t)row * 384 + k0 + c8 * 8;
      __builtin_amdgcn_global_load_lds((const __attribute__((address_space(1))) void*)gb,
                                       (__attribute__((address_space(3))) void*)&B1[c * 8],
                                       16, 0, 0);
    }
    __syncthreads();
#pragma unroll
    for (int kk = 0; kk < 2; ++kk) {
      short8 af[4], bf[6];
#pragma unroll
      for (int mi = 0; mi < 4; ++mi)
        af[mi] = *(const short8*)&A1[(mi * 16 + l15) * 64 + kk * 32 + l4 * 8];
#pragma unroll
      for (int ni = 0; ni < 6; ++ni)
        bf[ni] = *(const short8*)&B1[(wc * 96 + ni * 16 + l15) * 64 + kk * 32 + l4 * 8];
#pragma unroll
      for (int mi = 0; mi < 4; ++mi)
#pragma unroll
        for (int ni = 0; ni < 6; ++ni)
          acc1[mi][ni] = __builtin_amdgcn_mfma_f32_16x16x32_bf16(af[mi], bf[ni], acc1[mi][ni], 0, 0, 0);
    }
    __syncthreads();
  }
  // GELU -> H (LDS)
#pragma unroll
  for (int mi = 0; mi < 4; ++mi)
#pragma unroll
    for (int ni = 0; ni < 6; ++ni) {
      const int col = wc * 96 + ni * 16 + l15;
      const float bc = b1p[col];
#pragma unroll
      for (int r = 0; r < 4; ++r) {
        float v = acc1[mi][ni][r] + bc;
        v = 0.5f * v * (1.0f + erff(v * 0.70710678118654752f));
        H[(mi * 16 + l4 * 4 + r) * H_STRIDE + col] = f2b(v);
      }
    }
  __syncthreads();

  // ---------------- GEMM2: Y = H @ W2 + b2 ----------------
  f32x4 acc2[4][3] = {};
  for (int k0 = 0; k0 < 768; k0 += 64) {
#pragma unroll
    for (int s = 0; s < 6; ++s) {
      const int c = s * 512 + tid;           // < 3072
      const int row = c >> 3, c8 = c & 7;
      const u16* gb = W2T + (size_t)row * 768 + k0 + c8 * 8;
      __builtin_amdgcn_global_load_lds((const __attribute__((address_space(1))) void*)gb,
                                       (__attribute__((address_space(3))) void*)&B2[c * 8],
                                       16, 0, 0);
    }
    __syncthreads();
#pragma unroll
    for (int kk = 0; kk < 2; ++kk) {
      short8 af[4], bf[3];
#pragma unroll
      for (int mi = 0; mi < 4; ++mi)
        af[mi] = *(const short8*)&H[(mi * 16 + l15) * H_STRIDE + k0 + kk * 32 + l4 * 8];
#pragma unroll
      for (int ni = 0; ni < 3; ++ni)
        bf[ni] = *(const short8*)&B2[(wc * 48 + ni * 16 + l15) * 64 + kk * 32 + l4 * 8];
#pragma unroll
      for (int mi = 0; mi < 4; ++mi)
#pragma unroll
        for (int ni = 0; ni < 3; ++ni)
          acc2[mi][ni] = __builtin_amdgcn_mfma_f32_16x16x32_bf16(af[mi], bf[ni], acc2[mi][ni], 0, 0, 0);
    }
    __syncthreads();
  }

  // ---------------- LayerNorm (rows = windows, 384 cols across 8 waves) ----------------
  // add b2; per-(mi,r) partial sums over this wave's 3 ni, reduce over l15 group
  float rs1[4][4], rs2[4][4];
#pragma unroll
  for (int mi = 0; mi < 4; ++mi)
#pragma unroll
    for (int r = 0; r < 4; ++r) {
      float s1 = 0.f, s2 = 0.f;
#pragma unroll
      for (int ni = 0; ni < 3; ++ni) {
        const int col = wc * 48 + ni * 16 + l15;
        acc2[mi][ni][r] += b2[col];
        const float v = acc2[mi][ni][r];
        s1 += v; s2 += v * v;
      }
      rs1[mi][r] = s1; rs2[mi][r] = s2;
    }
#pragma unroll
  for (int off = 1; off < 16; off <<= 1) {
#pragma unroll
    for (int mi = 0; mi < 4; ++mi)
#pragma unroll
      for (int r = 0; r < 4; ++r) {
        rs1[mi][r] += __shfl_xor(rs1[mi][r], off, 64);
        rs2[mi][r] += __shfl_xor(rs2[mi][r], off, 64);
      }
  }
  if (l15 == 0) {
#pragma unroll
    for (int mi = 0; mi < 4; ++mi)
#pragma unroll
      for (int r = 0; r < 4; ++r) {
        const int row = mi * 16 + l4 * 4 + r;
        P1[row * 8 + wc] = rs1[mi][r];
        P2[row * 8 + wc] = rs2[mi][r];
      }
  }
  __syncthreads();
  if (tid < 64) {
    float s1 = 0.f, s2 = 0.f;
#pragma unroll
    for (int i = 0; i < 8; ++i) { s1 += P1[tid * 8 + i]; s2 += P2[tid * 8 + i]; }
    const float mu = s1 * (1.0f / 384.0f);
    const float var = s2 * (1.0f / 384.0f) - mu * mu;
    MU[tid] = mu;
    RS[tid] = rsqrtf(var + 1e-5f);
  }
  __syncthreads();
#pragma unroll
  for (int mi = 0; mi < 4; ++mi)
#pragma unroll
    for (int r = 0; r < 4; ++r) {
      const int row = mi * 16 + l4 * 4 + r;
      const float mu = MU[row], rstd = RS[row];
#pragma unroll
      for (int ni = 0; ni < 3; ++ni) {
        const int col = wc * 48 + ni * 16 + l15;
        out[(size_t)(w0 + row) * 384 + col] =
            (acc2[mi][ni][r] - mu) * rstd * gamma[col] + beta[col];
      }
    }
}

// ---------------- launch ----------------
extern "C" void kernel_launch(void* const* d_in, const int* in_sizes, int n_in,
                              void* d_out, int out_size, void* d_ws, size_t ws_size,
                              hipStream_t stream) {
  const float* x     = (const float*)d_in[0];
  const float* Wq    = (const float*)d_in[1];
  const float* bq    = (const float*)d_in[2];
  const float* Wk    = (const float*)d_in[3];
  // d_in[4] = bk: cancels in softmax, unused
  const float* Wv    = (const float*)d_in[5];
  const float* bv    = (const float*)d_in[6];
  const float* W1    = (const float*)d_in[7];
  const float* b1    = (const float*)d_in[8];
  const float* W2    = (const float*)d_in[9];
  const float* b2    = (const float*)d_in[10];
  const float* gamma = (const float*)d_in[11];
  const float* beta  = (const float*)d_in[12];

  char* ws = (char*)d_ws;
  u16*  Abuf = (u16*)(ws + 0);            // 25165824 B
  char* wb   = ws + 33554432;
  u16*  WqkT = (u16*)(wb);                // 294912 B
  u16*  W1pT = (u16*)(wb + 294912);       // 589824 B
  u16*  W2T  = (u16*)(wb + 884736);       // 589824 B
  float* bqk = (float*)(wb + 1474560);    // 1536 B
  float* b1p = (float*)(wb + 1476096);    // 3072 B

  prologue<<<3168, 256, 0, stream>>>(Wq, bq, Wk, Wv, bv, W1, b1, W2,
                                     WqkT, W1pT, W2T, bqk, b1p);
  k2a<<<256, 512, 0, stream>>>(x, WqkT, bqk, Abuf);
  mlp<<<512, 512, 0, stream>>>(Abuf, W1pT, b1p, W2T, b2, gamma, beta, (float*)d_out);
}